// Round 1
// baseline (15114.445 us; speedup 1.0000x reference)
//
#include <hip/hip_runtime.h>
#include <hip/hip_bf16.h>

#define SEQ    4096
#define HIDDEN 256
#define G3     768   // 3*HIDDEN

typedef __attribute__((ext_vector_type(8))) short bf16x8;
typedef __attribute__((ext_vector_type(4))) float f32x4;

__device__ __forceinline__ unsigned int pkbf(float a, float b) {
    __hip_bfloat162 h = __float22bfloat162_rn(make_float2(a, b));
    union { __hip_bfloat162 h2; unsigned int u; } c; c.h2 = h; return c.u;
}
__device__ __forceinline__ unsigned short f2bf(float a) {
    __hip_bfloat16 h = __float2bfloat16(a);
    union { __hip_bfloat16 h1; unsigned short u; } c; c.h1 = h; return c.u;
}
__device__ __forceinline__ float bflo(unsigned int q) { return __uint_as_float(q << 16); }
__device__ __forceinline__ float bfhi(unsigned int q) { return __uint_as_float(q & 0xFFFF0000u); }

// ---------------------------------------------------------------------------
// Kernel B: x_proj = x @ W_ih^T + (scaled, bias-folded), bf16, layout [t][g][b]
// Scales fold log2(e) into the gate pre-activations:
//   r rows: -log2e * (w,x,b_ih+b_hh) ; z rows: +log2e * (...) ; n rows: 2*log2e * (w,x,b_ih)
// grid (SEQ/32, 2), block 512 (8 waves). Wave owns 48 gate-cols (3 N-tiles).
// ---------------------------------------------------------------------------
__global__ __launch_bounds__(512, 2) void gru_xproj(
    const float* __restrict__ x, const float* __restrict__ w_ih,
    const float* __restrict__ b_ih, const float* __restrict__ b_hh,
    unsigned short* __restrict__ xg)
{
    __shared__ char alds[2][16384];   // [2 buf][32 rows][512 B], XOR-swizzled
    const int tid = threadIdx.x;
    const int lane = tid & 63, wave = tid >> 6;
    const int l15 = lane & 15, l4 = lane >> 4;
    const int t0 = blockIdx.x * 32;
    const int gbase = blockIdx.y * 384 + wave * 48;

    // weight fragments (3 N-tiles x 8 K-steps), scaled, in VGPRs
    bf16x8 wf[3][8];
    float bias[3];
    #pragma unroll
    for (int n = 0; n < 3; ++n) {
        const int g = gbase + n * 16 + l15;
        const float s = (g < 256) ? -1.442695041f : ((g < 512) ? 1.442695041f : 2.885390082f);
        bias[n] = (g < 512) ? s * (b_ih[g] + b_hh[g]) : s * b_ih[g];
        #pragma unroll
        for (int kk = 0; kk < 8; ++kk) {
            const float* p = w_ih + g * 256 + kk * 32 + l4 * 8;
            float4 aa = *(const float4*)(p);
            float4 bb = *(const float4*)(p + 4);
            union { bf16x8 v; unsigned int u[4]; } f;
            f.u[0] = pkbf(s * aa.x, s * aa.y); f.u[1] = pkbf(s * aa.z, s * aa.w);
            f.u[2] = pkbf(s * bb.x, s * bb.y); f.u[3] = pkbf(s * bb.z, s * bb.w);
            wf[n][kk] = f.v;
        }
    }

    for (int tt = 0; tt < 32; ++tt) {
        const int t = t0 + tt;
        const int buf = tt & 1;
        {   // stage x[:, t, :] -> bf16 LDS (swizzled)
            const int row = tid >> 4;           // batch 0..31
            const int k0  = (tid & 15) * 16;    // 16 floats each
            const float* xp = x + ((size_t)row * SEQ + t) * 256 + k0;
            float4 u0 = *(const float4*)(xp + 0);
            float4 u1 = *(const float4*)(xp + 4);
            float4 u2 = *(const float4*)(xp + 8);
            float4 u3 = *(const float4*)(xp + 12);
            union { bf16x8 v; unsigned int u[4]; } w0, w1;
            w0.u[0] = pkbf(u0.x,u0.y); w0.u[1] = pkbf(u0.z,u0.w);
            w0.u[2] = pkbf(u1.x,u1.y); w0.u[3] = pkbf(u1.z,u1.w);
            w1.u[0] = pkbf(u2.x,u2.y); w1.u[1] = pkbf(u2.z,u2.w);
            w1.u[2] = pkbf(u3.x,u3.y); w1.u[3] = pkbf(u3.z,u3.w);
            const int base = row * 512 + k0 * 2;
            const int swz  = (row & 7) << 4;
            *(bf16x8*)(alds[buf] + ((base     ) ^ swz)) = w0.v;
            *(bf16x8*)(alds[buf] + ((base + 16) ^ swz)) = w1.v;
        }
        __syncthreads();

        f32x4 acc[2][3];
        #pragma unroll
        for (int m = 0; m < 2; ++m)
            #pragma unroll
            for (int n = 0; n < 3; ++n) acc[m][n] = (f32x4){0.f,0.f,0.f,0.f};

        #pragma unroll
        for (int kk = 0; kk < 8; ++kk) {
            const int sw = (l15 & 7) << 4;
            bf16x8 a0 = *(const bf16x8*)(alds[buf] + (((l15     ) * 512 + kk * 64 + l4 * 16) ^ sw));
            bf16x8 a1 = *(const bf16x8*)(alds[buf] + (((l15 + 16) * 512 + kk * 64 + l4 * 16) ^ sw));
            #pragma unroll
            for (int n = 0; n < 3; ++n) {
                acc[0][n] = __builtin_amdgcn_mfma_f32_16x16x32_bf16(a0, wf[n][kk], acc[0][n], 0, 0, 0);
                acc[1][n] = __builtin_amdgcn_mfma_f32_16x16x32_bf16(a1, wf[n][kk], acc[1][n], 0, 0, 0);
            }
        }
        // store: xg[t][g][b], 4 packed bf16 (batch dir) per tile per lane
        #pragma unroll
        for (int m = 0; m < 2; ++m)
            #pragma unroll
            for (int n = 0; n < 3; ++n) {
                const int g = gbase + n * 16 + l15;
                uint2 q;
                q.x = pkbf(acc[m][n][0] + bias[n], acc[m][n][1] + bias[n]);
                q.y = pkbf(acc[m][n][2] + bias[n], acc[m][n][3] + bias[n]);
                *(uint2*)(xg + ((size_t)t * G3 + g) * 32 + m * 16 + l4 * 4) = q;
            }
    }
}

// ---------------------------------------------------------------------------
// Kernel C: persistent GRU scan. grid(2): block b owns batches [16b,16b+16).
// 8 waves; wave owns hidden cols [32w,32w+32) for all 3 gates (6 N-tiles).
// Tiles r,z in VGPRs; tiles n in LDS. h double-buffered bf16 in LDS (swizzled).
// ---------------------------------------------------------------------------
__global__ __launch_bounds__(512, 2) void gru_rec(
    const float* __restrict__ w_hh, const float* __restrict__ b_hh,
    const float* __restrict__ h0, const unsigned short* __restrict__ xg,
    float* __restrict__ out)
{
    extern __shared__ char smem[];
    char* hb  = smem;           // 2 x 8 KB h buffers
    char* bfr = smem + 16384;   // 128 KB n-gate B fragments
    const int tid = threadIdx.x, lane = tid & 63, wave = tid >> 6;
    const int l15 = lane & 15, l4 = lane >> 4;
    const int blk = blockIdx.x;
    const int j0 = wave * 32;

    bf16x8 wf[4][8];  // tiles g6=0..3 (r,z) in regs; g6=4,5 (n) -> LDS
    #pragma unroll
    for (int g6 = 0; g6 < 6; ++g6) {
        const int gate = g6 >> 1, jt = g6 & 1;
        const int row = gate * 256 + j0 + jt * 16 + l15;
        const float s = (gate == 0) ? -1.442695041f : ((gate == 1) ? 1.442695041f : 2.885390082f);
        #pragma unroll
        for (int kk = 0; kk < 8; ++kk) {
            const float* p = w_hh + row * 256 + kk * 32 + l4 * 8;
            float4 aa = *(const float4*)p;
            float4 bb = *(const float4*)(p + 4);
            union { bf16x8 v; unsigned int u[4]; } f;
            f.u[0] = pkbf(s * aa.x, s * aa.y); f.u[1] = pkbf(s * aa.z, s * aa.w);
            f.u[2] = pkbf(s * bb.x, s * bb.y); f.u[3] = pkbf(s * bb.z, s * bb.w);
            if (g6 < 4) wf[g6][kk] = f.v;
            else *(bf16x8*)(bfr + (((wave * 2 + (g6 - 4)) * 8 + kk) * 1024 + lane * 16)) = f.v;
        }
    }
    float bHn[2];
    bHn[0] = 2.885390082f * b_hh[512 + j0 + l15];
    bHn[1] = 2.885390082f * b_hh[512 + j0 + 16 + l15];

    // initial h: fp32 in regs + bf16 into hb buffer 0
    float hprev[2][4];
    #pragma unroll
    for (int jt = 0; jt < 2; ++jt)
        #pragma unroll
        for (int i = 0; i < 4; ++i) {
            const int b = blk * 16 + l4 * 4 + i;
            const int j = j0 + jt * 16 + l15;
            float h = h0[b * 256 + j];
            hprev[jt][i] = h;
            const int row = l4 * 4 + i;
            *(unsigned short*)(hb + ((row * 512 + j * 2) ^ ((row & 7) << 4))) = f2bf(h);
        }

    unsigned int eb[6];
    #pragma unroll
    for (int g6 = 0; g6 < 6; ++g6) {
        const int gate = g6 >> 1, jt = g6 & 1;
        eb[g6] = (unsigned)(gate * 256 + j0 + jt * 16 + l15) * 32u + (unsigned)(blk * 16 + l4 * 4);
    }
    float* outp = out + (size_t)(blk * 16 + l4 * 4) * SEQ * 256 + j0 + l15;

    uint2 xbuf[4][6];
#define XLOAD(B_, T_) do { _Pragma("unroll") \
    for (int g6_ = 0; g6_ < 6; ++g6_) \
        xbuf[B_][g6_] = *(const uint2*)(xg + (size_t)(T_) * 24576u + eb[g6_]); \
    } while (0)

    XLOAD(0, 0);
    XLOAD(1, 1);
    __syncthreads();

#define GATES(T_, C_, P_, JT_, AR, AZ, AN) do { \
    uint2 qr = xbuf[C_][0 + (JT_)], qz = xbuf[C_][2 + (JT_)], qn = xbuf[C_][4 + (JT_)]; \
    float xr[4] = { bflo(qr.x), bfhi(qr.x), bflo(qr.y), bfhi(qr.y) }; \
    float xz[4] = { bflo(qz.x), bfhi(qz.x), bflo(qz.y), bfhi(qz.y) }; \
    float xn[4] = { bflo(qn.x), bfhi(qn.x), bflo(qn.y), bfhi(qn.y) }; \
    _Pragma("unroll") for (int i = 0; i < 4; ++i) { \
        float r   = __builtin_amdgcn_rcpf(1.0f + __builtin_amdgcn_exp2f(AR[i] + xr[i])); \
        float uu  = __builtin_amdgcn_rcpf(1.0f + __builtin_amdgcn_exp2f(AZ[i] + xz[i])); \
        float hn  = AN[i] + bHn[JT_]; \
        float pre = fmaf(r, hn, xn[i]); \
        float nn  = fmaf(-2.0f, __builtin_amdgcn_rcpf(1.0f + __builtin_amdgcn_exp2f(pre)), 1.0f); \
        float hp  = hprev[JT_][i]; \
        float hnv = fmaf(uu, nn - hp, hp); \
        hprev[JT_][i] = hnv; \
        outp[(size_t)i * SEQ * 256 + (size_t)(T_) * 256 + (JT_) * 16] = hnv; \
        const int row_ = l4 * 4 + i; \
        *(unsigned short*)(hb + (1 - (P_)) * 8192 + \
            ((row_ * 512 + (j0 + (JT_) * 16 + l15) * 2) ^ ((row_ & 7) << 4))) = f2bf(hnv); \
    } } while (0)

#define BODY(T_, C_, N_, P_) do { \
    if ((T_) + 2 < SEQ) XLOAD(N_, (T_) + 2); \
    f32x4 z4 = {0.f,0.f,0.f,0.f}; \
    f32x4 acc0=z4, acc1=z4, acc2=z4, acc3=z4, acc4=z4, acc5=z4; \
    _Pragma("unroll") for (int kk = 0; kk < 8; ++kk) { \
        bf16x8 a_  = *(const bf16x8*)(hb + (P_) * 8192 + \
                        ((l15 * 512 + kk * 64 + l4 * 16) ^ ((l15 & 7) << 4))); \
        bf16x8 b4_ = *(const bf16x8*)(bfr + ((wave * 2 + 0) * 8 + kk) * 1024 + lane * 16); \
        bf16x8 b5_ = *(const bf16x8*)(bfr + ((wave * 2 + 1) * 8 + kk) * 1024 + lane * 16); \
        acc0 = __builtin_amdgcn_mfma_f32_16x16x32_bf16(a_, wf[0][kk], acc0, 0, 0, 0); \
        acc1 = __builtin_amdgcn_mfma_f32_16x16x32_bf16(a_, wf[1][kk], acc1, 0, 0, 0); \
        acc2 = __builtin_amdgcn_mfma_f32_16x16x32_bf16(a_, wf[2][kk], acc2, 0, 0, 0); \
        acc3 = __builtin_amdgcn_mfma_f32_16x16x32_bf16(a_, wf[3][kk], acc3, 0, 0, 0); \
        acc4 = __builtin_amdgcn_mfma_f32_16x16x32_bf16(a_, b4_, acc4, 0, 0, 0); \
        acc5 = __builtin_amdgcn_mfma_f32_16x16x32_bf16(a_, b5_, acc5, 0, 0, 0); \
    } \
    GATES(T_, C_, P_, 0, acc0, acc2, acc4); \
    GATES(T_, C_, P_, 1, acc1, acc3, acc5); \
    __syncthreads(); \
    } while (0)

    for (int tt = 0; tt < SEQ; tt += 4) {
        BODY(tt + 0, 0, 2, 0);
        BODY(tt + 1, 1, 3, 1);
        BODY(tt + 2, 2, 0, 0);
        BODY(tt + 3, 3, 1, 1);
    }
#undef BODY
#undef GATES
#undef XLOAD
}

extern "C" void kernel_launch(void* const* d_in, const int* in_sizes, int n_in,
                              void* d_out, int out_size, void* d_ws, size_t ws_size,
                              hipStream_t stream) {
    const float* x    = (const float*)d_in[0];
    const float* h0   = (const float*)d_in[1];
    const float* w_ih = (const float*)d_in[2];
    const float* w_hh = (const float*)d_in[3];
    const float* b_ih = (const float*)d_in[4];
    const float* b_hh = (const float*)d_in[5];
    float* out = (float*)d_out;
    unsigned short* xg = (unsigned short*)d_ws;   // needs SEQ*768*32*2 = 192 MB

    (void)in_sizes; (void)n_in; (void)out_size; (void)ws_size;

    hipFuncSetAttribute((const void*)gru_rec,
                        hipFuncAttributeMaxDynamicSharedMemorySize, 147456);

    gru_xproj<<<dim3(SEQ / 32, 2), dim3(512), 0, stream>>>(x, w_ih, b_ih, b_hh, xg);
    gru_rec<<<dim3(2), dim3(512), 147456, stream>>>(w_hh, b_hh, h0, xg, out);
}

// Round 2
// 10961.055 us; speedup vs baseline: 1.3789x; 1.3789x over previous
//
#include <hip/hip_runtime.h>
#include <hip/hip_bf16.h>

#define SEQ    4096
#define HIDDEN 256
#define G3     768   // 3*HIDDEN

typedef __attribute__((ext_vector_type(8))) short bf16x8;
typedef __attribute__((ext_vector_type(4))) float f32x4;

__device__ __forceinline__ unsigned int pkbf(float a, float b) {
    __hip_bfloat162 h = __float22bfloat162_rn(make_float2(a, b));
    union { __hip_bfloat162 h2; unsigned int u; } c; c.h2 = h; return c.u;
}
__device__ __forceinline__ unsigned short f2bf(float a) {
    __hip_bfloat16 h = __float2bfloat16(a);
    union { __hip_bfloat16 h1; unsigned short u; } c; c.h1 = h; return c.u;
}
__device__ __forceinline__ float bflo(unsigned int q) { return __uint_as_float(q << 16); }
__device__ __forceinline__ float bfhi(unsigned int q) { return __uint_as_float(q & 0xFFFF0000u); }

// ---------------------------------------------------------------------------
// Kernel B: x_proj = x @ W_ih^T (scaled, bias-folded), bf16, layout [t][g][b]
// r rows: -log2e*(...b_ih+b_hh) ; z rows: +log2e*(...) ; n rows: 2*log2e*(...b_ih)
// grid (SEQ/32, 2), block 512 (8 waves). Wave owns 48 gate-cols (3 N-tiles).
// ---------------------------------------------------------------------------
__global__ __launch_bounds__(512, 2) void gru_xproj(
    const float* __restrict__ x, const float* __restrict__ w_ih,
    const float* __restrict__ b_ih, const float* __restrict__ b_hh,
    unsigned short* __restrict__ xg)
{
    __shared__ __align__(16) char alds[2][16384];   // [2 buf][32 rows][512 B], XOR-swizzled
    const int tid = threadIdx.x;
    const int lane = tid & 63, wave = tid >> 6;
    const int l15 = lane & 15, l4 = lane >> 4;
    const int t0 = blockIdx.x * 32;
    const int gbase = blockIdx.y * 384 + wave * 48;

    bf16x8 wf[3][8];
    float bias[3];
    #pragma unroll
    for (int n = 0; n < 3; ++n) {
        const int g = gbase + n * 16 + l15;
        const float s = (g < 256) ? -1.442695041f : ((g < 512) ? 1.442695041f : 2.885390082f);
        bias[n] = (g < 512) ? s * (b_ih[g] + b_hh[g]) : s * b_ih[g];
        #pragma unroll
        for (int kk = 0; kk < 8; ++kk) {
            const float* p = w_ih + g * 256 + kk * 32 + l4 * 8;
            float4 aa = *(const float4*)(p);
            float4 bb = *(const float4*)(p + 4);
            union { bf16x8 v; unsigned int u[4]; } f;
            f.u[0] = pkbf(s * aa.x, s * aa.y); f.u[1] = pkbf(s * aa.z, s * aa.w);
            f.u[2] = pkbf(s * bb.x, s * bb.y); f.u[3] = pkbf(s * bb.z, s * bb.w);
            wf[n][kk] = f.v;
        }
    }

    for (int tt = 0; tt < 32; ++tt) {
        const int t = t0 + tt;
        const int buf = tt & 1;
        {
            const int row = tid >> 4;           // batch 0..31
            const int k0  = (tid & 15) * 16;    // 16 floats each
            const float* xp = x + ((size_t)row * SEQ + t) * 256 + k0;
            float4 u0 = *(const float4*)(xp + 0);
            float4 u1 = *(const float4*)(xp + 4);
            float4 u2 = *(const float4*)(xp + 8);
            float4 u3 = *(const float4*)(xp + 12);
            union { bf16x8 v; unsigned int u[4]; } w0, w1;
            w0.u[0] = pkbf(u0.x,u0.y); w0.u[1] = pkbf(u0.z,u0.w);
            w0.u[2] = pkbf(u1.x,u1.y); w0.u[3] = pkbf(u1.z,u1.w);
            w1.u[0] = pkbf(u2.x,u2.y); w1.u[1] = pkbf(u2.z,u2.w);
            w1.u[2] = pkbf(u3.x,u3.y); w1.u[3] = pkbf(u3.z,u3.w);
            const int base = row * 512 + k0 * 2;
            const int swz  = (row & 7) << 4;
            *(bf16x8*)(alds[buf] + ((base     ) ^ swz)) = w0.v;
            *(bf16x8*)(alds[buf] + ((base + 16) ^ swz)) = w1.v;
        }
        __syncthreads();

        f32x4 acc[2][3];
        #pragma unroll
        for (int m = 0; m < 2; ++m)
            #pragma unroll
            for (int n = 0; n < 3; ++n) acc[m][n] = (f32x4){0.f,0.f,0.f,0.f};

        #pragma unroll
        for (int kk = 0; kk < 8; ++kk) {
            const int sw = (l15 & 7) << 4;
            bf16x8 a0 = *(const bf16x8*)(alds[buf] + (((l15     ) * 512 + kk * 64 + l4 * 16) ^ sw));
            bf16x8 a1 = *(const bf16x8*)(alds[buf] + (((l15 + 16) * 512 + kk * 64 + l4 * 16) ^ sw));
            #pragma unroll
            for (int n = 0; n < 3; ++n) {
                acc[0][n] = __builtin_amdgcn_mfma_f32_16x16x32_bf16(a0, wf[n][kk], acc[0][n], 0, 0, 0);
                acc[1][n] = __builtin_amdgcn_mfma_f32_16x16x32_bf16(a1, wf[n][kk], acc[1][n], 0, 0, 0);
            }
        }
        #pragma unroll
        for (int m = 0; m < 2; ++m)
            #pragma unroll
            for (int n = 0; n < 3; ++n) {
                const int g = gbase + n * 16 + l15;
                uint2 q;
                q.x = pkbf(acc[m][n][0] + bias[n], acc[m][n][1] + bias[n]);
                q.y = pkbf(acc[m][n][2] + bias[n], acc[m][n][3] + bias[n]);
                *(uint2*)(xg + ((size_t)t * G3 + g) * 32 + m * 16 + l4 * 4) = q;
            }
    }
}

// ---------------------------------------------------------------------------
// Kernel C: persistent GRU scan. grid(2): block b owns batches [16b,16b+16).
// 8 waves; wave owns hidden cols [32w,32w+32) for all 3 gates = 6 N-tiles,
// ALL weight tiles in VGPRs (192). h double-buffered bf16 in LDS (swizzled).
// Raw s_barrier + lgkmcnt(0) only -- xg prefetch & out stores stay in flight.
// ---------------------------------------------------------------------------
__global__ __launch_bounds__(512) void gru_rec(
    const float* __restrict__ w_hh, const float* __restrict__ b_hh,
    const float* __restrict__ h0, const unsigned short* __restrict__ xg,
    float* __restrict__ out)
{
    __shared__ __align__(16) char hb[2][8192];
    const int tid = threadIdx.x, lane = tid & 63, wave = tid >> 6;
    const int l15 = lane & 15, l4 = lane >> 4;
    const int blk = blockIdx.x;
    const int j0 = wave * 32;

    // 6 weight tiles (r,z,n x jt0,jt1), scaled, fully in VGPRs: 192 regs
    bf16x8 wf[6][8];
    #pragma unroll
    for (int g6 = 0; g6 < 6; ++g6) {
        const int gate = g6 >> 1, jt = g6 & 1;
        const int row = gate * 256 + j0 + jt * 16 + l15;
        const float s = (gate == 0) ? -1.442695041f : ((gate == 1) ? 1.442695041f : 2.885390082f);
        #pragma unroll
        for (int kk = 0; kk < 8; ++kk) {
            const float* p = w_hh + row * 256 + kk * 32 + l4 * 8;
            float4 aa = *(const float4*)p;
            float4 bb = *(const float4*)(p + 4);
            union { bf16x8 v; unsigned int u[4]; } f;
            f.u[0] = pkbf(s * aa.x, s * aa.y); f.u[1] = pkbf(s * aa.z, s * aa.w);
            f.u[2] = pkbf(s * bb.x, s * bb.y); f.u[3] = pkbf(s * bb.z, s * bb.w);
            wf[g6][kk] = f.v;
        }
    }
    float bHn[2];
    bHn[0] = 2.885390082f * b_hh[512 + j0 + l15];
    bHn[1] = 2.885390082f * b_hh[512 + j0 + 16 + l15];

    // initial h: fp32 in regs + bf16 into hb buffer 0
    float hprev[2][4];
    #pragma unroll
    for (int jt = 0; jt < 2; ++jt)
        #pragma unroll
        for (int i = 0; i < 4; ++i) {
            const int b = blk * 16 + l4 * 4 + i;
            const int j = j0 + jt * 16 + l15;
            float h = h0[b * 256 + j];
            hprev[jt][i] = h;
            const int row = l4 * 4 + i;
            *(unsigned short*)(&hb[0][0] + ((row * 512 + j * 2) ^ ((row & 7) << 4))) = f2bf(h);
        }

    // per-gate xg slab pointers (advance 24576 elems = one t-slab per step)
    const int ebase = (j0 + l15) * 32 + blk * 16 + l4 * 4;
    const unsigned short* pg0 = xg + (size_t)(ebase);            // r gate
    const unsigned short* pg1 = xg + (size_t)(ebase + 8192);     // z gate
    const unsigned short* pg2 = xg + (size_t)(ebase + 16384);    // n gate
    float* outp = out + (size_t)(blk * 16 + l4 * 4) * SEQ * 256 + j0 + l15;

    uint2 xrz[4], xbn[2];
    xrz[0] = *(const uint2*)(pg0); xrz[1] = *(const uint2*)(pg0 + 512);
    xrz[2] = *(const uint2*)(pg1); xrz[3] = *(const uint2*)(pg1 + 512);
    xbn[0] = *(const uint2*)(pg2); xbn[1] = *(const uint2*)(pg2 + 512);
    pg0 += 24576; pg1 += 24576; pg2 += 24576;

    __builtin_amdgcn_sched_barrier(0);
    asm volatile("s_waitcnt lgkmcnt(0)" ::: "memory");
    __builtin_amdgcn_s_barrier();
    __builtin_amdgcn_sched_barrier(0);

#define GATES(T_, P_, JT_, AR, AZ, AN, QN) do { \
    float xn[4] = { bflo(QN.x), bfhi(QN.x), bflo(QN.y), bfhi(QN.y) }; \
    _Pragma("unroll") for (int i = 0; i < 4; ++i) { \
        float r   = __builtin_amdgcn_rcpf(1.0f + __builtin_amdgcn_exp2f(AR[i])); \
        float uu  = __builtin_amdgcn_rcpf(1.0f + __builtin_amdgcn_exp2f(AZ[i])); \
        float pre = fmaf(r, AN[i], xn[i]); \
        float nn  = fmaf(-2.0f, __builtin_amdgcn_rcpf(1.0f + __builtin_amdgcn_exp2f(pre)), 1.0f); \
        float hp  = hprev[JT_][i]; \
        float hnv = fmaf(uu, nn - hp, hp); \
        hprev[JT_][i] = hnv; \
        const int row_ = l4 * 4 + i; \
        *(unsigned short*)(&hb[1 - (P_)][0] + \
            ((row_ * 512 + (j0 + (JT_) * 16 + l15) * 2) ^ ((row_ & 7) << 4))) = f2bf(hnv); \
        outp[(size_t)i * SEQ * 256 + (size_t)(T_) * 256 + (JT_) * 16] = hnv; \
    } } while (0)

#define BODY(T_, P_) do { \
    f32x4 acc0 = { bflo(xrz[0].x), bfhi(xrz[0].x), bflo(xrz[0].y), bfhi(xrz[0].y) }; \
    f32x4 acc1 = { bflo(xrz[1].x), bfhi(xrz[1].x), bflo(xrz[1].y), bfhi(xrz[1].y) }; \
    f32x4 acc2 = { bflo(xrz[2].x), bfhi(xrz[2].x), bflo(xrz[2].y), bfhi(xrz[2].y) }; \
    f32x4 acc3 = { bflo(xrz[3].x), bfhi(xrz[3].x), bflo(xrz[3].y), bfhi(xrz[3].y) }; \
    f32x4 acc4 = { bHn[0], bHn[0], bHn[0], bHn[0] }; \
    f32x4 acc5 = { bHn[1], bHn[1], bHn[1], bHn[1] }; \
    xrz[0] = *(const uint2*)(pg0); xrz[1] = *(const uint2*)(pg0 + 512); \
    xrz[2] = *(const uint2*)(pg1); xrz[3] = *(const uint2*)(pg1 + 512); \
    _Pragma("unroll") for (int kk = 0; kk < 8; ++kk) { \
        bf16x8 a_ = *(const bf16x8*)(&hb[P_][0] + \
                        ((l15 * 512 + kk * 64 + l4 * 16) ^ ((l15 & 7) << 4))); \
        acc0 = __builtin_amdgcn_mfma_f32_16x16x32_bf16(a_, wf[0][kk], acc0, 0, 0, 0); \
        acc1 = __builtin_amdgcn_mfma_f32_16x16x32_bf16(a_, wf[1][kk], acc1, 0, 0, 0); \
        acc2 = __builtin_amdgcn_mfma_f32_16x16x32_bf16(a_, wf[2][kk], acc2, 0, 0, 0); \
        acc3 = __builtin_amdgcn_mfma_f32_16x16x32_bf16(a_, wf[3][kk], acc3, 0, 0, 0); \
        acc4 = __builtin_amdgcn_mfma_f32_16x16x32_bf16(a_, wf[4][kk], acc4, 0, 0, 0); \
        acc5 = __builtin_amdgcn_mfma_f32_16x16x32_bf16(a_, wf[5][kk], acc5, 0, 0, 0); \
    } \
    GATES(T_, P_, 0, acc0, acc2, acc4, xbn[0]); \
    GATES(T_, P_, 1, acc1, acc3, acc5, xbn[1]); \
    xbn[0] = *(const uint2*)(pg2); xbn[1] = *(const uint2*)(pg2 + 512); \
    if ((T_) + 2 < SEQ) { pg0 += 24576; pg1 += 24576; pg2 += 24576; } \
    __builtin_amdgcn_sched_barrier(0); \
    asm volatile("s_waitcnt lgkmcnt(0)" ::: "memory"); \
    __builtin_amdgcn_s_barrier(); \
    __builtin_amdgcn_sched_barrier(0); \
} while (0)

    for (int tt = 0; tt < SEQ; tt += 2) {
        BODY(tt + 0, 0);
        BODY(tt + 1, 1);
    }
#undef BODY
#undef GATES
}

extern "C" void kernel_launch(void* const* d_in, const int* in_sizes, int n_in,
                              void* d_out, int out_size, void* d_ws, size_t ws_size,
                              hipStream_t stream) {
    const float* x    = (const float*)d_in[0];
    const float* h0   = (const float*)d_in[1];
    const float* w_ih = (const float*)d_in[2];
    const float* w_hh = (const float*)d_in[3];
    const float* b_ih = (const float*)d_in[4];
    const float* b_hh = (const float*)d_in[5];
    float* out = (float*)d_out;
    unsigned short* xg = (unsigned short*)d_ws;   // needs SEQ*768*32*2 = 192 MB

    (void)in_sizes; (void)n_in; (void)out_size; (void)ws_size;

    gru_xproj<<<dim3(SEQ / 32, 2), dim3(512), 0, stream>>>(x, w_ih, b_ih, b_hh, xg);
    gru_rec<<<dim3(2), dim3(512), 0, stream>>>(w_hh, b_hh, h0, xg, out);
}